// Round 4
// baseline (245.678 us; speedup 1.0000x reference)
//
#include <hip/hip_runtime.h>
#include <math.h>

// Problem constants (B=4, N=2048, D=1024, DL=64, DK=128, DC=8)

// Workspace layout (float offsets). XBAR+BAR zeroed via hipMemsetAsync.
constexpr int XBAR_OFF = 0;       // B*1024  = 4096
constexpr int BAR_OFF  = 4096;    // 16 ints (barrier counters)
constexpr int SC_OFF   = 4112;    // B*16    = 64   [inv_tau, screen, czq0..7]
constexpr int QS_OFF   = 4176;    // B*128   = 512  q vectors
constexpr int US_OFF   = 4688;    // B*8*128 = 4096 u[b][r*128+j]
constexpr int AV_OFF   = 8784;    // B*9*1024= 36864 av[b][j][d]
constexpr int WZ_OFF   = 45648;   // B*N*8   = 65536 Wd . z_k
constexpr int DIST_OFF = 111184;  // B*N     = 8192
constexpr int S_OFF    = 119376;  // B*N     = 8192  raw scores
constexpr int WS_FLOATS = 127568;

constexpr int NBLK = 256;

__device__ __forceinline__ float wave_sum(float v) {
#pragma unroll
  for (int off = 32; off > 0; off >>= 1) v += __shfl_xor(v, off, 64);
  return v;
}

// Software grid barrier: per-phase counter, device-scope atomics.
__device__ __forceinline__ void gsync(int* bar, int phase) {
  __syncthreads();
  if (threadIdx.x == 0) {
    __threadfence();                 // release: drain + wb L2
    atomicAdd(bar + phase, 1);
    while (atomicAdd(bar + phase, 0) < NBLK) __builtin_amdgcn_s_sleep(8);
    __threadfence();                 // acquire: inv stale cache
  }
  __syncthreads();
}

// ---------------------------------------------------------------------------
// Single persistent kernel, 256 blocks (<=1 per CU guaranteed dispatchable).
//  P0: q (gamma inlined), wz/dist, scalars          (65 active blocks)
//  P1: u_r = skew_r^T q                             (64)
//  P2: av = WK^T [q|u] (+czq fold)                  (64)
//  P3: scores                                       (256, 32 n each)
//  P4: softmax (redundant) + weighted x-sum -> xbar (256)
//  P5: out = WO (WV xbar)                           (16)
// ---------------------------------------------------------------------------
__global__ __launch_bounds__(256) void k_fused(
    const float* __restrict__ xq, const float* __restrict__ zq,
    const float* __restrict__ x_keys, const float* __restrict__ z_keys,
    const float* __restrict__ WQ, const float* __restrict__ WQz,
    const float* __restrict__ G, const float* __restrict__ WK,
    const float* __restrict__ WV, const float* __restrict__ WO,
    const float* __restrict__ Wd, const float* __restrict__ bb,
    const float* __restrict__ be, const float* __restrict__ bo,
    const float* __restrict__ lsig, float* __restrict__ ws,
    float* __restrict__ out) {
  __shared__ __align__(16) float shm[9824];
  const int tid = threadIdx.x;
  const int blk = blockIdx.x;
  int* bar = (int*)(ws + BAR_OFF);

  // ========================= P0 =========================
  if (blk < 32) {
    // q[b,a] = WQ[a].xq[b] + WQz[a].zq[b] + sum_ij G[a,i,j] zq_i zq_j
    float* xqs = shm;           // 1024
    float* zqs = shm + 1024;    // 64
    float* part = shm + 1088;   // 256
    const int b = blk >> 3, as_ = blk & 7;
    for (int i = tid; i < 1024; i += 256) xqs[i] = xq[b * 1024 + i];
    if (tid < 64) zqs[tid] = zq[b * 64 + tid];
    __syncthreads();
    const int seg = tid & 15;
    const int a = as_ * 16 + (tid >> 4);
    const float4* wq4 = (const float4*)(WQ + a * 1024 + seg * 64);
    const float4* xs4 = (const float4*)(xqs + seg * 64);
    float p = 0;
#pragma unroll
    for (int c = 0; c < 16; ++c) {
      float4 w = wq4[c], x = xs4[c];
      p += w.x * x.x + w.y * x.y + w.z * x.z + w.w * x.w;
    }
#pragma unroll
    for (int c = 0; c < 4; ++c)
      p += WQz[a * 64 + seg * 4 + c] * zqs[seg * 4 + c];
    // gamma rows i = seg*4 .. +4
#pragma unroll
    for (int ii = 0; ii < 4; ++ii) {
      const int i = seg * 4 + ii;
      const float4* g4 = (const float4*)(G + a * 4096 + i * 64);
      float inner = 0;
#pragma unroll
      for (int c = 0; c < 16; ++c) {
        float4 gv = g4[c];
        const float4 zv = *(const float4*)(zqs + c * 4);
        inner += gv.x * zv.x + gv.y * zv.y + gv.z * zv.z + gv.w * zv.w;
      }
      p += zqs[i] * inner;
    }
    part[tid] = p;
    __syncthreads();
    if (tid < 16) {
      float s = 0;
#pragma unroll
      for (int h = 0; h < 16; ++h) s += part[tid * 16 + h];
      ws[QS_OFF + b * 128 + as_ * 16 + tid] = s;
    }
  } else if (blk < 64) {
    // per-position: wz[r] = Wd[r].z_k ; dist = |zq - zk|^2
    float* sWd = shm;          // 512
    float* zqs = shm + 512;    // 256
    sWd[tid] = Wd[tid];
    sWd[256 + tid] = Wd[256 + tid];
    zqs[tid] = zq[tid];
    __syncthreads();
    const int bn = (blk - 32) * 256 + tid;
    const int b = bn >> 11;
    const float4* zk4 = (const float4*)(z_keys + (size_t)bn * 64);
    const float* zqb = zqs + b * 64;
    float wzv[8] = {0, 0, 0, 0, 0, 0, 0, 0};
    float dist = 0;
    for (int l4 = 0; l4 < 16; ++l4) {
      float4 z4 = zk4[l4];
      float ze[4] = {z4.x, z4.y, z4.z, z4.w};
#pragma unroll
      for (int e = 0; e < 4; ++e) {
        const int l = l4 * 4 + e;
        float z = ze[e];
        float dz = zqb[l] - z;
        dist += dz * dz;
#pragma unroll
        for (int r = 0; r < 8; ++r) wzv[r] += sWd[r * 64 + l] * z;
      }
    }
#pragma unroll
    for (int r = 0; r < 8; ++r) ws[WZ_OFF + bn * 8 + r] = wzv[r];
    ws[DIST_OFF + bn] = dist;
  } else if (blk == 64) {
    // per-batch scalars + czq (wave w handles batch b=w)
    float* zqs = shm;
    zqs[tid] = zq[tid];
    __syncthreads();
    const int b = tid >> 6, l = tid & 63;
    float z = zqs[b * 64 + l];
    float r2 = wave_sum(z * z);
    float cz[8];
#pragma unroll
    for (int r = 0; r < 8; ++r) cz[r] = wave_sum(Wd[r * 64 + l] * z);
    if (l == 0) {
      r2 = fminf(r2, 1.0f - 1e-6f);
      float lam = 2.0f / (1.0f - r2 + 1e-6f);
      ws[SC_OFF + b * 16 + 0] = lam / sqrtf(128.0f);               // 1/tau
      ws[SC_OFF + b * 16 + 1] = expf(lsig[0]) * 0.5f * lam * lam;  // screen
#pragma unroll
      for (int r = 0; r < 8; ++r) ws[SC_OFF + b * 16 + 2 + r] = cz[r];
    }
  }
  gsync(bar, 0);

  // ========================= P1: u =========================
  // blk = r*8 + jc; j in [jc*16, jc*16+16). thread = (is, jl): is covers 8 i's.
  if (blk < 64) {
    const int r = blk >> 3, jc = blk & 7;
    float* sq = shm;          // 512
    float* red = shm + 512;   // 1024
    for (int o = tid; o < 512; o += 256) sq[o] = ws[QS_OFF + o];
    __syncthreads();
    const int jl = tid & 15, is = tid >> 4;
    const int j = jc * 16 + jl;
    float acc[4] = {0, 0, 0, 0};
    const float* arrs[3] = {bb, be, bo};
    const float wgt[3] = {1.0f, 0.5f, 0.3f};
#pragma unroll
    for (int arr = 0; arr < 3; ++arr) {
      const float w = wgt[arr];
      const float* base = arrs[arr] + r * 16384;
#pragma unroll
      for (int k = 0; k < 8; ++k) {
        const int i = is * 8 + k;
        const float sk = w * (base[i * 128 + j] - base[j * 128 + i]);
#pragma unroll
        for (int b = 0; b < 4; ++b) acc[b] += sk * sq[b * 128 + i];
      }
    }
#pragma unroll
    for (int b = 0; b < 4; ++b) red[(jl * 4 + b) * 16 + is] = acc[b];
    __syncthreads();
    if (tid < 64) {
      const int jl2 = tid >> 2, b = tid & 3;
      float s = 0;
#pragma unroll
      for (int is2 = 0; is2 < 16; ++is2) s += red[(jl2 * 4 + b) * 16 + is2];
      ws[US_OFF + b * 1024 + r * 128 + jc * 16 + jl2] = s;
    }
  }
  gsync(bar, 1);

  // ========================= P2: av =========================
  if (blk < 64) {
    const int b = blk >> 4, dbase = (blk & 15) * 64;
    float* qu = shm;            // 1152
    float* part = shm + 1152;   // 2304
    float* fin = shm + 3456;    // 576
    float* czq = shm + 4032;    // 8
    for (int o = tid; o < 1152; o += 256)
      qu[o] = (o < 128) ? ws[QS_OFF + b * 128 + o]
                        : ws[US_OFF + b * 1024 + (o - 128)];
    if (tid < 8) czq[tid] = ws[SC_OFF + b * 16 + 2 + tid];
    __syncthreads();
    const int kq = tid >> 6, dloc = tid & 63;
    float acc[9];
#pragma unroll
    for (int jj = 0; jj < 9; ++jj) acc[jj] = 0;
    const float* wkp = WK + dbase + dloc;
#pragma unroll 4
    for (int k = kq * 32; k < kq * 32 + 32; ++k) {
      const float wk = wkp[k * 1024];
#pragma unroll
      for (int jj = 0; jj < 9; ++jj) acc[jj] += qu[jj * 128 + k] * wk;
    }
#pragma unroll
    for (int jj = 0; jj < 9; ++jj) part[kq * 576 + jj * 64 + dloc] = acc[jj];
    __syncthreads();
    for (int o = tid; o < 576; o += 256)
      fin[o] = part[o] + part[576 + o] + part[1152 + o] + part[1728 + o];
    __syncthreads();
    float* av = ws + AV_OFF + b * 9216;
    for (int o = tid; o < 576; o += 256) {
      const int jj = o >> 6, dl = o & 63;
      float val = fin[o];
      if (jj == 0) {
#pragma unroll
        for (int rr = 0; rr < 8; ++rr)
          val += czq[rr] * fin[(1 + rr) * 64 + dl];
      }
      av[jj * 1024 + dbase + dl] = val;
    }
  }
  gsync(bar, 2);

  // ========================= P3: scores =========================
  {
    float* sav = shm;  // 9216 (+inv_tau at [9216])
    const int b = blk >> 6;
    const float* avg = ws + AV_OFF + b * 9216;
    for (int i = tid * 4; i < 9216; i += 1024)
      *(float4*)(sav + i) = *(const float4*)(avg + i);
    if (tid == 0) shm[9216] = ws[SC_OFF + b * 16];  // inv_tau
    __syncthreads();

    const int wave = tid >> 6, lane = tid & 63;
    for (int half = 0; half < 2; ++half) {
      const int nbase = (blk & 63) * 32 + half * 16 + wave * 4;
      const float* xb = x_keys + ((size_t)(b * 2048 + nbase)) * 1024;

      float acc[9][4];
#pragma unroll
      for (int j = 0; j < 9; ++j)
#pragma unroll
        for (int p = 0; p < 4; ++p) acc[j][p] = 0;

#pragma unroll
      for (int c = 0; c < 4; ++c) {
        const int off = c * 256 + lane * 4;
        float4 xv[4];
#pragma unroll
        for (int p = 0; p < 4; ++p)
          xv[p] = *(const float4*)(xb + p * 1024 + off);
#pragma unroll
        for (int j = 0; j < 9; ++j) {
          float4 a = *(const float4*)(sav + j * 1024 + off);
#pragma unroll
          for (int p = 0; p < 4; ++p)
            acc[j][p] +=
                a.x * xv[p].x + a.y * xv[p].y + a.z * xv[p].z + a.w * xv[p].w;
        }
      }
#pragma unroll
      for (int j = 0; j < 9; ++j)
#pragma unroll
        for (int p = 0; p < 4; ++p) acc[j][p] = wave_sum(acc[j][p]);

      if (lane == 0) {
        const float it = shm[9216];
        for (int p = 0; p < 4; ++p) {
          const int bn = b * 2048 + nbase + p;
          const float* wz = ws + WZ_OFF + bn * 8;
          float s = acc[0][p];
#pragma unroll
          for (int r = 0; r < 8; ++r) s -= wz[r] * acc[1 + r][p];
          ws[S_OFF + bn] = s * it;
        }
      }
    }
  }
  gsync(bar, 3);

  // ========================= P4: softmax + xbar =========================
  {
    const int b = blk >> 6, loc = blk & 63, nt = loc >> 2, dsl = loc & 3;
    float* red = shm;        // 256
    float* sw = shm + 256;   // 128
    float sv[8];
    float vmax = -1e30f;
#pragma unroll
    for (int i = 0; i < 8; ++i) {
      sv[i] = ws[S_OFF + b * 2048 + i * 256 + tid];
      vmax = fmaxf(vmax, sv[i]);
    }
    red[tid] = vmax;
    __syncthreads();
    for (int s = 128; s > 0; s >>= 1) {
      if (tid < s) red[tid] = fmaxf(red[tid], red[tid + s]);
      __syncthreads();
    }
    const float m = red[0];
    __syncthreads();
    float lsum = 0;
#pragma unroll
    for (int i = 0; i < 8; ++i) lsum += expf(sv[i] - m);
    red[tid] = lsum;
    __syncthreads();
    for (int s = 128; s > 0; s >>= 1) {
      if (tid < s) red[tid] += red[tid + s];
      __syncthreads();
    }
    const float rl = 1.0f / red[0];
    const float screen = ws[SC_OFF + b * 16 + 1];
    const int n0 = nt * 128;
    if (tid < 128) {
      const int n = n0 + tid;
      sw[tid] = expf(ws[S_OFF + b * 2048 + n] - m -
                     screen * ws[DIST_OFF + b * 2048 + n]) * rl;
    }
    __syncthreads();
    const int d = dsl * 256 + tid;
    const float* xb = x_keys + ((size_t)(b * 2048 + n0)) * 1024 + d;
    float a0 = 0, a1 = 0, a2 = 0, a3 = 0;
    for (int n = 0; n < 128; n += 4) {
      a0 += sw[n + 0] * xb[(size_t)(n + 0) * 1024];
      a1 += sw[n + 1] * xb[(size_t)(n + 1) * 1024];
      a2 += sw[n + 2] * xb[(size_t)(n + 2) * 1024];
      a3 += sw[n + 3] * xb[(size_t)(n + 3) * 1024];
    }
    atomicAdd(&ws[XBAR_OFF + b * 1024 + d], (a0 + a1) + (a2 + a3));
  }
  gsync(bar, 4);

  // ========================= P5: out =========================
  if (blk < 16) {
    const int b = blk >> 2, dsl = blk & 3;
    float* sx = shm;          // 1024
    float* sy = shm + 1024;   // 128
    for (int i = tid; i < 1024; i += 256) sx[i] = ws[XBAR_OFF + b * 1024 + i];
    __syncthreads();
    const int wave = tid >> 6, lane = tid & 63;
    for (int t = 0; t < 32; ++t) {
      const int dk = wave * 32 + t;
      const float4* wv4 = (const float4*)(WV + dk * 1024 + lane * 16);
      const float4* xs4 = (const float4*)(sx + lane * 16);
      float p = 0;
#pragma unroll
      for (int c = 0; c < 4; ++c) {
        float4 w4 = wv4[c], x4 = xs4[c];
        p += w4.x * x4.x + w4.y * x4.y + w4.z * x4.z + w4.w * x4.w;
      }
      p = wave_sum(p);
      if (lane == 0) sy[dk] = p;
    }
    __syncthreads();
    const int d = dsl * 256 + tid;
    const float4* wo4 = (const float4*)(WO + d * 128);
    float acc = 0;
#pragma unroll
    for (int c = 0; c < 32; ++c) {
      float4 w = wo4[c];
      acc += w.x * sy[c * 4 + 0] + w.y * sy[c * 4 + 1] +
             w.z * sy[c * 4 + 2] + w.w * sy[c * 4 + 3];
    }
    out[b * 1024 + d] = acc;
  }
}

// ---------------------------------------------------------------------------
extern "C" void kernel_launch(void* const* d_in, const int* in_sizes, int n_in,
                              void* d_out, int out_size, void* d_ws,
                              size_t ws_size, hipStream_t stream) {
  const float* xq  = (const float*)d_in[0];
  const float* zq  = (const float*)d_in[1];
  const float* xk  = (const float*)d_in[2];
  const float* zk  = (const float*)d_in[3];
  const float* WQ  = (const float*)d_in[4];
  const float* WQz = (const float*)d_in[5];
  const float* G   = (const float*)d_in[6];
  const float* WK  = (const float*)d_in[7];
  const float* WV  = (const float*)d_in[8];
  const float* WO  = (const float*)d_in[9];
  const float* Wd  = (const float*)d_in[10];
  const float* bb  = (const float*)d_in[11];
  const float* be  = (const float*)d_in[12];
  const float* bo  = (const float*)d_in[13];
  const float* ls  = (const float*)d_in[14];
  float* ws  = (float*)d_ws;
  float* out = (float*)d_out;
  if (ws_size < (size_t)WS_FLOATS * sizeof(float)) return;

  // Zero xbar accumulators + barrier counters (ws is poisoned every call).
  hipMemsetAsync(ws, 0, (size_t)(4096 + 16) * sizeof(float), stream);

  hipLaunchKernelGGL(k_fused, dim3(NBLK), dim3(256), 0, stream,
                     xq, zq, xk, zk, WQ, WQz, G, WK, WV, WO, Wd, bb, be, bo,
                     ls, ws, out);
}

// Round 5
// 212.248 us; speedup vs baseline: 1.1575x; 1.1575x over previous
//
#include <hip/hip_runtime.h>
#include <math.h>

// Problem constants (B=4, N=2048, D=1024, DL=64, DK=128, DC=8)

// Workspace layout (float offsets). ws is poisoned 0xAA before EVERY launch;
// ctrl init + xbar zeroing are done in-kernel (MAGIC-flag protocol).
constexpr int XBAR_OFF = 0;       // B*1024  = 4096
constexpr int CTRL_OFF = 4096;    // 2816 int slots (flag, roots, leaves)
constexpr int SC_OFF   = 6912;    // B*16    = 64   [inv_tau, screen, czq0..7]
constexpr int QS_OFF   = 6976;    // B*128   = 512  q vectors
constexpr int US_OFF   = 7488;    // B*8*128 = 4096 u[b][r*128+j]
constexpr int AV_OFF   = 11584;   // B*9*1024= 36864 av[b][j][d]
constexpr int WZ_OFF   = 48448;   // B*N*8   = 65536 Wd . z_k
constexpr int DIST_OFF = 113984;  // B*N     = 8192
constexpr int S_OFF    = 122176;  // B*N     = 8192  raw scores
constexpr int WS_FLOATS = 130368;

constexpr int NBLK = 256;
constexpr int MAGIC = 0x1F2E3D4C;
// ctrl int layout (stride 32 ints = 128 B per line):
//   [0]            ready flag
//   [32*(1+p)]     root counter, phase p (0..4)
//   [32*(6+p*16+g)] leaf counter, phase p, leaf g (0..15)
constexpr int CTRL_INTS = 32 * (6 + 5 * 16);  // 2752

__device__ __forceinline__ float wave_sum(float v) {
#pragma unroll
  for (int off = 32; off > 0; off >>= 1) v += __shfl_xor(v, off, 64);
  return v;
}

// Two-level software grid barrier. Load-only spin, tree arrival.
__device__ __forceinline__ void gsync(int* ctrl, int phase, int blk) {
  __syncthreads();
  if (threadIdx.x == 0) {
    __threadfence();  // release: make this block's writes device-visible
    if (phase == 0) {
      // wait for block 0's ctrl init (flag starts as poison 0xAAAAAAAA)
      while (__hip_atomic_load(ctrl, __ATOMIC_ACQUIRE,
                               __HIP_MEMORY_SCOPE_AGENT) != MAGIC)
        __builtin_amdgcn_s_sleep(8);
    }
    int* leaf = ctrl + 32 * (6 + phase * 16 + (blk & 15));
    int* root = ctrl + 32 * (1 + phase);
    int old = __hip_atomic_fetch_add(leaf, 1, __ATOMIC_RELAXED,
                                     __HIP_MEMORY_SCOPE_AGENT);
    if (old == 15)
      __hip_atomic_fetch_add(root, 1, __ATOMIC_RELAXED,
                             __HIP_MEMORY_SCOPE_AGENT);
    while (__hip_atomic_load(root, __ATOMIC_RELAXED,
                             __HIP_MEMORY_SCOPE_AGENT) < 16)
      __builtin_amdgcn_s_sleep(16);
    __threadfence();  // acquire: invalidate stale cached data
  }
  __syncthreads();
}

// ---------------------------------------------------------------------------
// Single persistent kernel, 256 blocks (capacity 4/CU at 39 KB LDS, so all
// blocks are resident — software barrier is deadlock-safe).
//  P0: q (gamma inlined), wz/dist, scalars, xbar zero   (69 active blocks)
//  P1: u_r = skew_r^T q                                 (64)
//  P2: av = WK^T [q|u] (+czq fold)                      (64)
//  P3: scores                                           (256, 32 n each)
//  P4: softmax (redundant) + weighted x-sum -> xbar     (256)
//  P5: out = WO (WV xbar)                               (16)
// ---------------------------------------------------------------------------
__global__ __launch_bounds__(256) void k_fused(
    const float* __restrict__ xq, const float* __restrict__ zq,
    const float* __restrict__ x_keys, const float* __restrict__ z_keys,
    const float* __restrict__ WQ, const float* __restrict__ WQz,
    const float* __restrict__ G, const float* __restrict__ WK,
    const float* __restrict__ WV, const float* __restrict__ WO,
    const float* __restrict__ Wd, const float* __restrict__ bb,
    const float* __restrict__ be, const float* __restrict__ bo,
    const float* __restrict__ lsig, float* __restrict__ ws,
    float* __restrict__ out) {
  __shared__ __align__(16) float shm[9824];
  const int tid = threadIdx.x;
  const int blk = blockIdx.x;
  int* ctrl = (int*)(ws + CTRL_OFF);

  // ---- ctrl init (block 0) ----
  if (blk == 0) {
    for (int i = tid; i < CTRL_INTS; i += 256) ctrl[i] = 0;
    __syncthreads();
    if (tid == 0) {
      __threadfence();
      __hip_atomic_store(ctrl, MAGIC, __ATOMIC_RELEASE,
                         __HIP_MEMORY_SCOPE_AGENT);
    }
  }

  // ========================= P0 =========================
  if (blk < 32) {
    // q[b,a] = WQ[a].xq[b] + WQz[a].zq[b] + sum_ij G[a,i,j] zq_i zq_j
    float* xqs = shm;           // 1024
    float* zqs = shm + 1024;    // 64
    float* part = shm + 1088;   // 256
    const int b = blk >> 3, as_ = blk & 7;
    for (int i = tid; i < 1024; i += 256) xqs[i] = xq[b * 1024 + i];
    if (tid < 64) zqs[tid] = zq[b * 64 + tid];
    __syncthreads();
    const int seg = tid & 15;
    const int a = as_ * 16 + (tid >> 4);
    const float4* wq4 = (const float4*)(WQ + a * 1024 + seg * 64);
    const float4* xs4 = (const float4*)(xqs + seg * 64);
    float p = 0;
#pragma unroll
    for (int c = 0; c < 16; ++c) {
      float4 w = wq4[c], x = xs4[c];
      p += w.x * x.x + w.y * x.y + w.z * x.z + w.w * x.w;
    }
#pragma unroll
    for (int c = 0; c < 4; ++c)
      p += WQz[a * 64 + seg * 4 + c] * zqs[seg * 4 + c];
    // gamma rows i = seg*4 .. +4
#pragma unroll
    for (int ii = 0; ii < 4; ++ii) {
      const int i = seg * 4 + ii;
      const float4* g4 = (const float4*)(G + a * 4096 + i * 64);
      float inner = 0;
#pragma unroll
      for (int c = 0; c < 16; ++c) {
        float4 gv = g4[c];
        const float4 zv = *(const float4*)(zqs + c * 4);
        inner += gv.x * zv.x + gv.y * zv.y + gv.z * zv.z + gv.w * zv.w;
      }
      p += zqs[i] * inner;
    }
    part[tid] = p;
    __syncthreads();
    if (tid < 16) {
      float s = 0;
#pragma unroll
      for (int h = 0; h < 16; ++h) s += part[tid * 16 + h];
      ws[QS_OFF + b * 128 + as_ * 16 + tid] = s;
    }
  } else if (blk < 64) {
    // per-position: wz[r] = Wd[r].z_k ; dist = |zq - zk|^2
    float* sWd = shm;          // 512
    float* zqs = shm + 512;    // 256
    sWd[tid] = Wd[tid];
    sWd[256 + tid] = Wd[256 + tid];
    zqs[tid] = zq[tid];
    __syncthreads();
    const int bn = (blk - 32) * 256 + tid;
    const int b = bn >> 11;
    const float4* zk4 = (const float4*)(z_keys + (size_t)bn * 64);
    const float* zqb = zqs + b * 64;
    float wzv[8] = {0, 0, 0, 0, 0, 0, 0, 0};
    float dist = 0;
    for (int l4 = 0; l4 < 16; ++l4) {
      float4 z4 = zk4[l4];
      float ze[4] = {z4.x, z4.y, z4.z, z4.w};
#pragma unroll
      for (int e = 0; e < 4; ++e) {
        const int l = l4 * 4 + e;
        float z = ze[e];
        float dz = zqb[l] - z;
        dist += dz * dz;
#pragma unroll
        for (int r = 0; r < 8; ++r) wzv[r] += sWd[r * 64 + l] * z;
      }
    }
#pragma unroll
    for (int r = 0; r < 8; ++r) ws[WZ_OFF + bn * 8 + r] = wzv[r];
    ws[DIST_OFF + bn] = dist;
  } else if (blk == 64) {
    // per-batch scalars + czq (wave w handles batch b=w)
    float* zqs = shm;
    zqs[tid] = zq[tid];
    __syncthreads();
    const int b = tid >> 6, l = tid & 63;
    float z = zqs[b * 64 + l];
    float r2 = wave_sum(z * z);
    float cz[8];
#pragma unroll
    for (int r = 0; r < 8; ++r) cz[r] = wave_sum(Wd[r * 64 + l] * z);
    if (l == 0) {
      r2 = fminf(r2, 1.0f - 1e-6f);
      float lam = 2.0f / (1.0f - r2 + 1e-6f);
      ws[SC_OFF + b * 16 + 0] = lam / sqrtf(128.0f);               // 1/tau
      ws[SC_OFF + b * 16 + 1] = expf(lsig[0]) * 0.5f * lam * lam;  // screen
#pragma unroll
      for (int r = 0; r < 8; ++r) ws[SC_OFF + b * 16 + 2 + r] = cz[r];
    }
  } else if (blk < 69) {
    const int b = blk - 65;
    for (int i = tid; i < 1024; i += 256) ws[XBAR_OFF + b * 1024 + i] = 0.0f;
  }
  gsync(ctrl, 0, blk);

  // ========================= P1: u =========================
  // blk = r*8 + jc; j in [jc*16, jc*16+16). thread = (is, jl): is covers 8 i's.
  if (blk < 64) {
    const int r = blk >> 3, jc = blk & 7;
    float* sq = shm;          // 512
    float* red = shm + 512;   // 1024
    for (int o = tid; o < 512; o += 256) sq[o] = ws[QS_OFF + o];
    __syncthreads();
    const int jl = tid & 15, is = tid >> 4;
    const int j = jc * 16 + jl;
    float acc[4] = {0, 0, 0, 0};
    const float* arrs[3] = {bb, be, bo};
    const float wgt[3] = {1.0f, 0.5f, 0.3f};
#pragma unroll
    for (int arr = 0; arr < 3; ++arr) {
      const float w = wgt[arr];
      const float* base = arrs[arr] + r * 16384;
#pragma unroll
      for (int k = 0; k < 8; ++k) {
        const int i = is * 8 + k;
        const float sk = w * (base[i * 128 + j] - base[j * 128 + i]);
#pragma unroll
        for (int b = 0; b < 4; ++b) acc[b] += sk * sq[b * 128 + i];
      }
    }
#pragma unroll
    for (int b = 0; b < 4; ++b) red[(jl * 4 + b) * 16 + is] = acc[b];
    __syncthreads();
    if (tid < 64) {
      const int jl2 = tid >> 2, b = tid & 3;
      float s = 0;
#pragma unroll
      for (int is2 = 0; is2 < 16; ++is2) s += red[(jl2 * 4 + b) * 16 + is2];
      ws[US_OFF + b * 1024 + r * 128 + jc * 16 + jl2] = s;
    }
  }
  gsync(ctrl, 1, blk);

  // ========================= P2: av =========================
  if (blk < 64) {
    const int b = blk >> 4, dbase = (blk & 15) * 64;
    float* qu = shm;            // 1152
    float* part = shm + 1152;   // 2304
    float* fin = shm + 3456;    // 576
    float* czq = shm + 4032;    // 8
    for (int o = tid; o < 1152; o += 256)
      qu[o] = (o < 128) ? ws[QS_OFF + b * 128 + o]
                        : ws[US_OFF + b * 1024 + (o - 128)];
    if (tid < 8) czq[tid] = ws[SC_OFF + b * 16 + 2 + tid];
    __syncthreads();
    const int kq = tid >> 6, dloc = tid & 63;
    float acc[9];
#pragma unroll
    for (int jj = 0; jj < 9; ++jj) acc[jj] = 0;
    const float* wkp = WK + dbase + dloc;
#pragma unroll 4
    for (int k = kq * 32; k < kq * 32 + 32; ++k) {
      const float wk = wkp[k * 1024];
#pragma unroll
      for (int jj = 0; jj < 9; ++jj) acc[jj] += qu[jj * 128 + k] * wk;
    }
#pragma unroll
    for (int jj = 0; jj < 9; ++jj) part[kq * 576 + jj * 64 + dloc] = acc[jj];
    __syncthreads();
    for (int o = tid; o < 576; o += 256)
      fin[o] = part[o] + part[576 + o] + part[1152 + o] + part[1728 + o];
    __syncthreads();
    float* av = ws + AV_OFF + b * 9216;
    for (int o = tid; o < 576; o += 256) {
      const int jj = o >> 6, dl = o & 63;
      float val = fin[o];
      if (jj == 0) {
#pragma unroll
        for (int rr = 0; rr < 8; ++rr)
          val += czq[rr] * fin[(1 + rr) * 64 + dl];
      }
      av[jj * 1024 + dbase + dl] = val;
    }
  }
  gsync(ctrl, 2, blk);

  // ========================= P3: scores =========================
  {
    float* sav = shm;  // 9216 (+inv_tau at [9216])
    const int b = blk >> 6;
    const float* avg = ws + AV_OFF + b * 9216;
    for (int i = tid * 4; i < 9216; i += 1024)
      *(float4*)(sav + i) = *(const float4*)(avg + i);
    if (tid == 0) shm[9216] = ws[SC_OFF + b * 16];  // inv_tau
    __syncthreads();

    const int wave = tid >> 6, lane = tid & 63;
    for (int half = 0; half < 2; ++half) {
      const int nbase = (blk & 63) * 32 + half * 16 + wave * 4;
      const float* xb = x_keys + ((size_t)(b * 2048 + nbase)) * 1024;

      float acc[9][4];
#pragma unroll
      for (int j = 0; j < 9; ++j)
#pragma unroll
        for (int p = 0; p < 4; ++p) acc[j][p] = 0;

#pragma unroll
      for (int c = 0; c < 4; ++c) {
        const int off = c * 256 + lane * 4;
        float4 xv[4];
#pragma unroll
        for (int p = 0; p < 4; ++p)
          xv[p] = *(const float4*)(xb + p * 1024 + off);
#pragma unroll
        for (int j = 0; j < 9; ++j) {
          float4 a = *(const float4*)(sav + j * 1024 + off);
#pragma unroll
          for (int p = 0; p < 4; ++p)
            acc[j][p] +=
                a.x * xv[p].x + a.y * xv[p].y + a.z * xv[p].z + a.w * xv[p].w;
        }
      }
#pragma unroll
      for (int j = 0; j < 9; ++j)
#pragma unroll
        for (int p = 0; p < 4; ++p) acc[j][p] = wave_sum(acc[j][p]);

      if (lane == 0) {
        const float it = shm[9216];
        for (int p = 0; p < 4; ++p) {
          const int bn = b * 2048 + nbase + p;
          const float* wz = ws + WZ_OFF + bn * 8;
          float s = acc[0][p];
#pragma unroll
          for (int r = 0; r < 8; ++r) s -= wz[r] * acc[1 + r][p];
          ws[S_OFF + bn] = s * it;
        }
      }
    }
  }
  gsync(ctrl, 3, blk);

  // ========================= P4: softmax + xbar =========================
  {
    const int b = blk >> 6, loc = blk & 63, nt = loc >> 2, dsl = loc & 3;
    float* red = shm;        // 256
    float* sw = shm + 256;   // 128
    float sv[8];
    float vmax = -1e30f;
#pragma unroll
    for (int i = 0; i < 8; ++i) {
      sv[i] = ws[S_OFF + b * 2048 + i * 256 + tid];
      vmax = fmaxf(vmax, sv[i]);
    }
    red[tid] = vmax;
    __syncthreads();
    for (int s = 128; s > 0; s >>= 1) {
      if (tid < s) red[tid] = fmaxf(red[tid], red[tid + s]);
      __syncthreads();
    }
    const float m = red[0];
    __syncthreads();
    float lsum = 0;
#pragma unroll
    for (int i = 0; i < 8; ++i) lsum += expf(sv[i] - m);
    red[tid] = lsum;
    __syncthreads();
    for (int s = 128; s > 0; s >>= 1) {
      if (tid < s) red[tid] += red[tid + s];
      __syncthreads();
    }
    const float rl = 1.0f / red[0];
    const float screen = ws[SC_OFF + b * 16 + 1];
    const int n0 = nt * 128;
    if (tid < 128) {
      const int n = n0 + tid;
      sw[tid] = expf(ws[S_OFF + b * 2048 + n] - m -
                     screen * ws[DIST_OFF + b * 2048 + n]) * rl;
    }
    __syncthreads();
    const int d = dsl * 256 + tid;
    const float* xb = x_keys + ((size_t)(b * 2048 + n0)) * 1024 + d;
    float a0 = 0, a1 = 0, a2 = 0, a3 = 0;
    for (int n = 0; n < 128; n += 4) {
      a0 += sw[n + 0] * xb[(size_t)(n + 0) * 1024];
      a1 += sw[n + 1] * xb[(size_t)(n + 1) * 1024];
      a2 += sw[n + 2] * xb[(size_t)(n + 2) * 1024];
      a3 += sw[n + 3] * xb[(size_t)(n + 3) * 1024];
    }
    atomicAdd(&ws[XBAR_OFF + b * 1024 + d], (a0 + a1) + (a2 + a3));
  }
  gsync(ctrl, 4, blk);

  // ========================= P5: out =========================
  if (blk < 16) {
    const int b = blk >> 2, dsl = blk & 3;
    float* sx = shm;          // 1024
    float* sy = shm + 1024;   // 128
    for (int i = tid; i < 1024; i += 256) sx[i] = ws[XBAR_OFF + b * 1024 + i];
    __syncthreads();
    const int wave = tid >> 6, lane = tid & 63;
    for (int t = 0; t < 32; ++t) {
      const int dk = wave * 32 + t;
      const float4* wv4 = (const float4*)(WV + dk * 1024 + lane * 16);
      const float4* xs4 = (const float4*)(sx + lane * 16);
      float p = 0;
#pragma unroll
      for (int c = 0; c < 4; ++c) {
        float4 w4 = wv4[c], x4 = xs4[c];
        p += w4.x * x4.x + w4.y * x4.y + w4.z * x4.z + w4.w * x4.w;
      }
      p = wave_sum(p);
      if (lane == 0) sy[dk] = p;
    }
    __syncthreads();
    const int d = dsl * 256 + tid;
    const float4* wo4 = (const float4*)(WO + d * 128);
    float acc = 0;
#pragma unroll
    for (int c = 0; c < 32; ++c) {
      float4 w = wo4[c];
      acc += w.x * sy[c * 4 + 0] + w.y * sy[c * 4 + 1] +
             w.z * sy[c * 4 + 2] + w.w * sy[c * 4 + 3];
    }
    out[b * 1024 + d] = acc;
  }
}

// ---------------------------------------------------------------------------
extern "C" void kernel_launch(void* const* d_in, const int* in_sizes, int n_in,
                              void* d_out, int out_size, void* d_ws,
                              size_t ws_size, hipStream_t stream) {
  const float* xq  = (const float*)d_in[0];
  const float* zq  = (const float*)d_in[1];
  const float* xk  = (const float*)d_in[2];
  const float* zk  = (const float*)d_in[3];
  const float* WQ  = (const float*)d_in[4];
  const float* WQz = (const float*)d_in[5];
  const float* G   = (const float*)d_in[6];
  const float* WK  = (const float*)d_in[7];
  const float* WV  = (const float*)d_in[8];
  const float* WO  = (const float*)d_in[9];
  const float* Wd  = (const float*)d_in[10];
  const float* bb  = (const float*)d_in[11];
  const float* be  = (const float*)d_in[12];
  const float* bo  = (const float*)d_in[13];
  const float* ls  = (const float*)d_in[14];
  float* ws  = (float*)d_ws;
  float* out = (float*)d_out;
  if (ws_size < (size_t)WS_FLOATS * sizeof(float)) return;

  hipLaunchKernelGGL(k_fused, dim3(NBLK), dim3(256), 0, stream,
                     xq, zq, xk, zk, WQ, WQz, G, WK, WV, WO, Wd, bb, be, bo,
                     ls, ws, out);
}

// Round 6
// 174.705 us; speedup vs baseline: 1.4062x; 1.2149x over previous
//
#include <hip/hip_runtime.h>
#include <math.h>

// Problem constants (B=4, N=2048, D=1024, DL=64, DK=128, DC=8)

// Workspace layout (float offsets). ws is poisoned 0xAA before EVERY launch;
// ctrl init + xbar zeroing are done in-kernel (MAGIC-flag protocol).
// ALL inter-phase intermediates are WRITTEN via relaxed agent-scope atomic
// stores (sc1 -> coherence point, bypassing the non-coherent per-XCD L2) and
// READ via normal cached vectorized loads (safe: first normal touch of those
// lines happens strictly after the producing barrier; kernel-dispatch
// boundaries invalidate L2 across graph replays).
constexpr int XBAR_OFF = 0;       // B*1024  = 4096
constexpr int CTRL_OFF = 4096;    // 2816 int slots (flag, roots, leaves)
constexpr int SC_OFF   = 6912;    // B*16    = 64   [inv_tau, screen, czq0..7]
constexpr int QS_OFF   = 6976;    // B*128   = 512  q vectors
constexpr int US_OFF   = 7488;    // B*8*128 = 4096 u[b][r*128+j]
constexpr int AV_OFF   = 11584;   // B*9*1024= 36864 av[b][j][d]
constexpr int WZ_OFF   = 48448;   // B*N*8   = 65536 Wd . z_k
constexpr int DIST_OFF = 113984;  // B*N     = 8192
constexpr int S_OFF    = 122176;  // B*N     = 8192  raw scores
constexpr int WS_FLOATS = 130368;

constexpr int NBLK = 256;
constexpr int MAGIC = 0x1F2E3D4C;
// ctrl int layout (stride 32 ints = 128 B per line):
//   [0]             ready flag
//   [32*(1+p)]      root counter, phase p (0..4)
//   [32*(6+p*16+g)] leaf counter, phase p, leaf g (0..15)
constexpr int CTRL_INTS = 32 * (6 + 5 * 16);  // 2752

__device__ __forceinline__ float wave_sum(float v) {
#pragma unroll
  for (int off = 32; off > 0; off >>= 1) v += __shfl_xor(v, off, 64);
  return v;
}

// Publish a float to the coherence point (bypasses non-coherent L2).
__device__ __forceinline__ void pub(float* p, float v) {
  __hip_atomic_store(p, v, __ATOMIC_RELAXED, __HIP_MEMORY_SCOPE_AGENT);
}

// Fence-free two-level grid barrier. Correctness: __syncthreads drains all
// waves' outstanding vm stores before s_barrier (measured codegen, m97); all
// data was published via sc1 atomic stores, so once tid0 increments the
// counter every prior write is at the coherence point. Consumers' loads issue
// in-order after the spin resolves. No L2 writeback/invalidate needed.
__device__ __forceinline__ void gsync(int* ctrl, int phase, int blk) {
  __syncthreads();
  if (threadIdx.x == 0) {
    __builtin_amdgcn_s_waitcnt(0);  // belt & suspenders for wave 0
    if (phase == 0) {
      // wait for block 0's ctrl init (flag starts as poison 0xAAAAAAAA)
      while (__hip_atomic_load(ctrl, __ATOMIC_RELAXED,
                               __HIP_MEMORY_SCOPE_AGENT) != MAGIC)
        __builtin_amdgcn_s_sleep(2);
    }
    int* leaf = ctrl + 32 * (6 + phase * 16 + (blk & 15));
    int* root = ctrl + 32 * (1 + phase);
    if (__hip_atomic_fetch_add(leaf, 1, __ATOMIC_RELAXED,
                               __HIP_MEMORY_SCOPE_AGENT) == 15)
      __hip_atomic_fetch_add(root, 1, __ATOMIC_RELAXED,
                             __HIP_MEMORY_SCOPE_AGENT);
    while (__hip_atomic_load(root, __ATOMIC_RELAXED,
                             __HIP_MEMORY_SCOPE_AGENT) < 16)
      __builtin_amdgcn_s_sleep(4);
  }
  __asm__ volatile("" ::: "memory");
  __syncthreads();
}

// ---------------------------------------------------------------------------
// Single persistent kernel, 256 blocks (capacity 4/CU at 39 KB LDS, so all
// blocks are resident — software barrier is deadlock-safe).
//  P0: q (gamma inlined), wz/dist, scalars, xbar zero   (69 active blocks)
//  P1: u_r = skew_r^T q                                 (64)
//  P2: av = WK^T [q|u] (+czq fold)                      (64)
//  P3: scores                                           (256, 32 n each)
//  P4: softmax (redundant) + weighted x-sum -> xbar     (256)
//  P5: out = WO (WV xbar)                               (16)
// ---------------------------------------------------------------------------
__global__ __launch_bounds__(256) void k_fused(
    const float* __restrict__ xq, const float* __restrict__ zq,
    const float* __restrict__ x_keys, const float* __restrict__ z_keys,
    const float* __restrict__ WQ, const float* __restrict__ WQz,
    const float* __restrict__ G, const float* __restrict__ WK,
    const float* __restrict__ WV, const float* __restrict__ WO,
    const float* __restrict__ Wd, const float* __restrict__ bb,
    const float* __restrict__ be, const float* __restrict__ bo,
    const float* __restrict__ lsig, float* __restrict__ ws,
    float* __restrict__ out) {
  __shared__ __align__(16) float shm[9824];
  const int tid = threadIdx.x;
  const int blk = blockIdx.x;
  int* ctrl = (int*)(ws + CTRL_OFF);

  // ---- ctrl init (block 0): atomic stores only, then flag ----
  if (blk == 0) {
    for (int i = tid; i < CTRL_INTS; i += 256)
      __hip_atomic_store(ctrl + i, 0, __ATOMIC_RELAXED,
                         __HIP_MEMORY_SCOPE_AGENT);
    __syncthreads();  // drains all waves' stores
    if (tid == 0)
      __hip_atomic_store(ctrl, MAGIC, __ATOMIC_RELAXED,
                         __HIP_MEMORY_SCOPE_AGENT);
  }

  // ========================= P0 =========================
  if (blk < 32) {
    // q[b,a] = WQ[a].xq[b] + WQz[a].zq[b] + sum_ij G[a,i,j] zq_i zq_j
    float* xqs = shm;           // 1024
    float* zqs = shm + 1024;    // 64
    float* part = shm + 1088;   // 256
    const int b = blk >> 3, as_ = blk & 7;
    for (int i = tid; i < 1024; i += 256) xqs[i] = xq[b * 1024 + i];
    if (tid < 64) zqs[tid] = zq[b * 64 + tid];
    __syncthreads();
    const int seg = tid & 15;
    const int a = as_ * 16 + (tid >> 4);
    const float4* wq4 = (const float4*)(WQ + a * 1024 + seg * 64);
    const float4* xs4 = (const float4*)(xqs + seg * 64);
    float p = 0;
#pragma unroll
    for (int c = 0; c < 16; ++c) {
      float4 w = wq4[c], x = xs4[c];
      p += w.x * x.x + w.y * x.y + w.z * x.z + w.w * x.w;
    }
#pragma unroll
    for (int c = 0; c < 4; ++c)
      p += WQz[a * 64 + seg * 4 + c] * zqs[seg * 4 + c];
    // gamma rows i = seg*4 .. +4
#pragma unroll
    for (int ii = 0; ii < 4; ++ii) {
      const int i = seg * 4 + ii;
      const float4* g4 = (const float4*)(G + a * 4096 + i * 64);
      float inner = 0;
#pragma unroll
      for (int c = 0; c < 16; ++c) {
        float4 gv = g4[c];
        const float4 zv = *(const float4*)(zqs + c * 4);
        inner += gv.x * zv.x + gv.y * zv.y + gv.z * zv.z + gv.w * zv.w;
      }
      p += zqs[i] * inner;
    }
    part[tid] = p;
    __syncthreads();
    if (tid < 16) {
      float s = 0;
#pragma unroll
      for (int h = 0; h < 16; ++h) s += part[tid * 16 + h];
      pub(&ws[QS_OFF + b * 128 + as_ * 16 + tid], s);
    }
  } else if (blk < 64) {
    // per-position: wz[r] = Wd[r].z_k ; dist = |zq - zk|^2
    float* sWd = shm;          // 512
    float* zqs = shm + 512;    // 256
    sWd[tid] = Wd[tid];
    sWd[256 + tid] = Wd[256 + tid];
    zqs[tid] = zq[tid];
    __syncthreads();
    const int bn = (blk - 32) * 256 + tid;
    const int b = bn >> 11;
    const float4* zk4 = (const float4*)(z_keys + (size_t)bn * 64);
    const float* zqb = zqs + b * 64;
    float wzv[8] = {0, 0, 0, 0, 0, 0, 0, 0};
    float dist = 0;
    for (int l4 = 0; l4 < 16; ++l4) {
      float4 z4 = zk4[l4];
      float ze[4] = {z4.x, z4.y, z4.z, z4.w};
#pragma unroll
      for (int e = 0; e < 4; ++e) {
        const int l = l4 * 4 + e;
        float z = ze[e];
        float dz = zqb[l] - z;
        dist += dz * dz;
#pragma unroll
        for (int r = 0; r < 8; ++r) wzv[r] += sWd[r * 64 + l] * z;
      }
    }
#pragma unroll
    for (int r = 0; r < 8; ++r) pub(&ws[WZ_OFF + bn * 8 + r], wzv[r]);
    pub(&ws[DIST_OFF + bn], dist);
  } else if (blk == 64) {
    // per-batch scalars + czq (wave w handles batch b=w)
    float* zqs = shm;
    zqs[tid] = zq[tid];
    __syncthreads();
    const int b = tid >> 6, l = tid & 63;
    float z = zqs[b * 64 + l];
    float r2 = wave_sum(z * z);
    float cz[8];
#pragma unroll
    for (int r = 0; r < 8; ++r) cz[r] = wave_sum(Wd[r * 64 + l] * z);
    if (l == 0) {
      r2 = fminf(r2, 1.0f - 1e-6f);
      float lam = 2.0f / (1.0f - r2 + 1e-6f);
      pub(&ws[SC_OFF + b * 16 + 0], lam / sqrtf(128.0f));            // 1/tau
      pub(&ws[SC_OFF + b * 16 + 1], expf(lsig[0]) * 0.5f * lam * lam);
#pragma unroll
      for (int r = 0; r < 8; ++r) pub(&ws[SC_OFF + b * 16 + 2 + r], cz[r]);
    }
  } else if (blk < 69) {
    const int b = blk - 65;
    for (int i = tid; i < 1024; i += 256)
      pub(&ws[XBAR_OFF + b * 1024 + i], 0.0f);
  }
  gsync(ctrl, 0, blk);

  // ========================= P1: u =========================
  // blk = r*8 + jc; j in [jc*16, jc*16+16). thread = (is, jl): is covers 8 i's.
  if (blk < 64) {
    const int r = blk >> 3, jc = blk & 7;
    float* sq = shm;          // 512
    float* red = shm + 512;   // 1024
    for (int o = tid; o < 512; o += 256) sq[o] = ws[QS_OFF + o];
    __syncthreads();
    const int jl = tid & 15, is = tid >> 4;
    const int j = jc * 16 + jl;
    float acc[4] = {0, 0, 0, 0};
    const float* arrs[3] = {bb, be, bo};
    const float wgt[3] = {1.0f, 0.5f, 0.3f};
#pragma unroll
    for (int arr = 0; arr < 3; ++arr) {
      const float w = wgt[arr];
      const float* base = arrs[arr] + r * 16384;
#pragma unroll
      for (int k = 0; k < 8; ++k) {
        const int i = is * 8 + k;
        const float sk = w * (base[i * 128 + j] - base[j * 128 + i]);
#pragma unroll
        for (int b = 0; b < 4; ++b) acc[b] += sk * sq[b * 128 + i];
      }
    }
#pragma unroll
    for (int b = 0; b < 4; ++b) red[(jl * 4 + b) * 16 + is] = acc[b];
    __syncthreads();
    if (tid < 64) {
      const int jl2 = tid >> 2, b = tid & 3;
      float s = 0;
#pragma unroll
      for (int is2 = 0; is2 < 16; ++is2) s += red[(jl2 * 4 + b) * 16 + is2];
      pub(&ws[US_OFF + b * 1024 + r * 128 + jc * 16 + jl2], s);
    }
  }
  gsync(ctrl, 1, blk);

  // ========================= P2: av =========================
  if (blk < 64) {
    const int b = blk >> 4, dbase = (blk & 15) * 64;
    float* qu = shm;            // 1152
    float* part = shm + 1152;   // 2304
    float* fin = shm + 3456;    // 576
    float* czq = shm + 4032;    // 8
    for (int o = tid; o < 1152; o += 256)
      qu[o] = (o < 128) ? ws[QS_OFF + b * 128 + o]
                        : ws[US_OFF + b * 1024 + (o - 128)];
    if (tid < 8) czq[tid] = ws[SC_OFF + b * 16 + 2 + tid];
    __syncthreads();
    const int kq = tid >> 6, dloc = tid & 63;
    float acc[9];
#pragma unroll
    for (int jj = 0; jj < 9; ++jj) acc[jj] = 0;
    const float* wkp = WK + dbase + dloc;
#pragma unroll 4
    for (int k = kq * 32; k < kq * 32 + 32; ++k) {
      const float wk = wkp[k * 1024];
#pragma unroll
      for (int jj = 0; jj < 9; ++jj) acc[jj] += qu[jj * 128 + k] * wk;
    }
#pragma unroll
    for (int jj = 0; jj < 9; ++jj) part[kq * 576 + jj * 64 + dloc] = acc[jj];
    __syncthreads();
    for (int o = tid; o < 576; o += 256)
      fin[o] = part[o] + part[576 + o] + part[1152 + o] + part[1728 + o];
    __syncthreads();
    float* av = ws + AV_OFF + b * 9216;
    for (int o = tid; o < 576; o += 256) {
      const int jj = o >> 6, dl = o & 63;
      float val = fin[o];
      if (jj == 0) {
#pragma unroll
        for (int rr = 0; rr < 8; ++rr)
          val += czq[rr] * fin[(1 + rr) * 64 + dl];
      }
      pub(&av[jj * 1024 + dbase + dl], val);
    }
  }
  gsync(ctrl, 2, blk);

  // ========================= P3: scores =========================
  {
    float* sav = shm;  // 9216 (+inv_tau at [9216])
    const int b = blk >> 6;
    const float* avg = ws + AV_OFF + b * 9216;
    for (int i = tid * 4; i < 9216; i += 1024)
      *(float4*)(sav + i) = *(const float4*)(avg + i);
    if (tid == 0) shm[9216] = ws[SC_OFF + b * 16];  // inv_tau
    __syncthreads();

    const int wave = tid >> 6, lane = tid & 63;
    for (int half = 0; half < 2; ++half) {
      const int nbase = (blk & 63) * 32 + half * 16 + wave * 4;
      const float* xb = x_keys + ((size_t)(b * 2048 + nbase)) * 1024;

      float acc[9][4];
#pragma unroll
      for (int j = 0; j < 9; ++j)
#pragma unroll
        for (int p = 0; p < 4; ++p) acc[j][p] = 0;

#pragma unroll
      for (int c = 0; c < 4; ++c) {
        const int off = c * 256 + lane * 4;
        float4 xv[4];
#pragma unroll
        for (int p = 0; p < 4; ++p)
          xv[p] = *(const float4*)(xb + p * 1024 + off);
#pragma unroll
        for (int j = 0; j < 9; ++j) {
          float4 a = *(const float4*)(sav + j * 1024 + off);
#pragma unroll
          for (int p = 0; p < 4; ++p)
            acc[j][p] +=
                a.x * xv[p].x + a.y * xv[p].y + a.z * xv[p].z + a.w * xv[p].w;
        }
      }
#pragma unroll
      for (int j = 0; j < 9; ++j)
#pragma unroll
        for (int p = 0; p < 4; ++p) acc[j][p] = wave_sum(acc[j][p]);

      if (lane == 0) {
        const float it = shm[9216];
        for (int p = 0; p < 4; ++p) {
          const int bn = b * 2048 + nbase + p;
          const float* wz = ws + WZ_OFF + bn * 8;
          float s = acc[0][p];
#pragma unroll
          for (int r = 0; r < 8; ++r) s -= wz[r] * acc[1 + r][p];
          pub(&ws[S_OFF + bn], s * it);
        }
      }
    }
  }
  gsync(ctrl, 3, blk);

  // ========================= P4: softmax + xbar =========================
  {
    const int b = blk >> 6, loc = blk & 63, nt = loc >> 2, dsl = loc & 3;
    float* red = shm;        // 256
    float* sw = shm + 256;   // 128
    float sv[8];
    float vmax = -1e30f;
#pragma unroll
    for (int i = 0; i < 8; ++i) {
      sv[i] = ws[S_OFF + b * 2048 + i * 256 + tid];
      vmax = fmaxf(vmax, sv[i]);
    }
    red[tid] = vmax;
    __syncthreads();
    for (int s = 128; s > 0; s >>= 1) {
      if (tid < s) red[tid] = fmaxf(red[tid], red[tid + s]);
      __syncthreads();
    }
    const float m = red[0];
    __syncthreads();
    float lsum = 0;
#pragma unroll
    for (int i = 0; i < 8; ++i) lsum += expf(sv[i] - m);
    red[tid] = lsum;
    __syncthreads();
    for (int s = 128; s > 0; s >>= 1) {
      if (tid < s) red[tid] += red[tid + s];
      __syncthreads();
    }
    const float rl = 1.0f / red[0];
    const float screen = ws[SC_OFF + b * 16 + 1];
    const int n0 = nt * 128;
    if (tid < 128) {
      const int n = n0 + tid;
      sw[tid] = expf(ws[S_OFF + b * 2048 + n] - m -
                     screen * ws[DIST_OFF + b * 2048 + n]) * rl;
    }
    __syncthreads();
    const int d = dsl * 256 + tid;
    const float* xb = x_keys + ((size_t)(b * 2048 + n0)) * 1024 + d;
    float a0 = 0, a1 = 0, a2 = 0, a3 = 0;
    for (int n = 0; n < 128; n += 4) {
      a0 += sw[n + 0] * xb[(size_t)(n + 0) * 1024];
      a1 += sw[n + 1] * xb[(size_t)(n + 1) * 1024];
      a2 += sw[n + 2] * xb[(size_t)(n + 2) * 1024];
      a3 += sw[n + 3] * xb[(size_t)(n + 3) * 1024];
    }
    atomicAdd(&ws[XBAR_OFF + b * 1024 + d], (a0 + a1) + (a2 + a3));
  }
  gsync(ctrl, 4, blk);

  // ========================= P5: out =========================
  if (blk < 16) {
    const int b = blk >> 2, dsl = blk & 3;
    float* sx = shm;          // 1024
    float* sy = shm + 1024;   // 128
    for (int i = tid; i < 1024; i += 256) sx[i] = ws[XBAR_OFF + b * 1024 + i];
    __syncthreads();
    const int wave = tid >> 6, lane = tid & 63;
    for (int t = 0; t < 32; ++t) {
      const int dk = wave * 32 + t;
      const float4* wv4 = (const float4*)(WV + dk * 1024 + lane * 16);
      const float4* xs4 = (const float4*)(sx + lane * 16);
      float p = 0;
#pragma unroll
      for (int c = 0; c < 4; ++c) {
        float4 w4 = wv4[c], x4 = xs4[c];
        p += w4.x * x4.x + w4.y * x4.y + w4.z * x4.z + w4.w * x4.w;
      }
      p = wave_sum(p);
      if (lane == 0) sy[dk] = p;
    }
    __syncthreads();
    const int d = dsl * 256 + tid;
    const float4* wo4 = (const float4*)(WO + d * 128);
    float acc = 0;
#pragma unroll
    for (int c = 0; c < 32; ++c) {
      float4 w = wo4[c];
      acc += w.x * sy[c * 4 + 0] + w.y * sy[c * 4 + 1] +
             w.z * sy[c * 4 + 2] + w.w * sy[c * 4 + 3];
    }
    out[b * 1024 + d] = acc;
  }
}

// ---------------------------------------------------------------------------
extern "C" void kernel_launch(void* const* d_in, const int* in_sizes, int n_in,
                              void* d_out, int out_size, void* d_ws,
                              size_t ws_size, hipStream_t stream) {
  const float* xq  = (const float*)d_in[0];
  const float* zq  = (const float*)d_in[1];
  const float* xk  = (const float*)d_in[2];
  const float* zk  = (const float*)d_in[3];
  const float* WQ  = (const float*)d_in[4];
  const float* WQz = (const float*)d_in[5];
  const float* G   = (const float*)d_in[6];
  const float* WK  = (const float*)d_in[7];
  const float* WV  = (const float*)d_in[8];
  const float* WO  = (const float*)d_in[9];
  const float* Wd  = (const float*)d_in[10];
  const float* bb  = (const float*)d_in[11];
  const float* be  = (const float*)d_in[12];
  const float* bo  = (const float*)d_in[13];
  const float* ls  = (const float*)d_in[14];
  float* ws  = (float*)d_ws;
  float* out = (float*)d_out;
  if (ws_size < (size_t)WS_FLOATS * sizeof(float)) return;

  hipLaunchKernelGGL(k_fused, dim3(NBLK), dim3(256), 0, stream,
                     xq, zq, xk, zk, WQ, WQz, G, WK, WV, WO, Wd, bb, be, bo,
                     ls, ws, out);
}